// Round 18
// baseline (619.293 us; speedup 1.0000x reference)
//
#include <hip/hip_runtime.h>
#include <stdint.h>

typedef unsigned short u16;
using bf16x8 = __attribute__((ext_vector_type(8))) __bf16;
using f32x4  = __attribute__((ext_vector_type(4))) float;

#define MFMA16(a,b,c) __builtin_amdgcn_mfma_f32_16x16x32_bf16((a),(b),(c),0,0,0)

__device__ __forceinline__ u16 f2bf(float f) {
  union { float f; uint32_t u; } v; v.f = f;
  uint32_t r = v.u + 0x7FFFu + ((v.u >> 16) & 1u);
  return (u16)(r >> 16);
}
__device__ __forceinline__ float bf2f(u16 u) {
  union { uint32_t u; float f; } v; v.u = ((uint32_t)u) << 16;
  return v.f;
}

// async global->LDS, 16B per lane; lds ptr must be wave-uniform (HW: base + lane*16)
__device__ __forceinline__ void gload_lds16(const void* g, void* l) {
  typedef const __attribute__((address_space(1))) void* gp_t;
  typedef __attribute__((address_space(3))) void* lp_t;
  __builtin_amdgcn_global_load_lds((gp_t)(uintptr_t)g,
                                   (lp_t)(uint32_t)(uintptr_t)l, 16, 0, 0);
}

// ==== prep_k: fused {4x weight cast+transpose} + {adaLN stage 1} ====
__global__ __launch_bounds__(256)
void prep_k(const float* __restrict__ w_qkv, const float* __restrict__ w_proj,
            const float* __restrict__ w_mlp1, const float* __restrict__ w_mlp2,
            u16* __restrict__ oq, u16* __restrict__ op,
            u16* __restrict__ o1, u16* __restrict__ o2,
            const float* __restrict__ c, const float* __restrict__ w_ada,
            float* __restrict__ partial) {
  int bid = blockIdx.x;
  if (bid >= 3072) {
    bid -= 3072;
    const int jb = bid % 24, ks = bid / 24;
    const int j = jb * 256 + threadIdx.x;
    __shared__ float sil[8][32];
    {
      int b = threadIdx.x >> 5, kk = threadIdx.x & 31;
      float v = c[b * 1024 + ks * 32 + kk];
      sil[b][kk] = v / (1.f + __expf(-v));
    }
    __syncthreads();
    float acc[8] = {0,0,0,0,0,0,0,0};
#pragma unroll 8
    for (int kk = 0; kk < 32; ++kk) {
      float wv = w_ada[(size_t)(ks * 32 + kk) * 6144 + j];
#pragma unroll
      for (int b = 0; b < 8; ++b) acc[b] += sil[b][kk] * wv;
    }
#pragma unroll
    for (int b = 0; b < 8; ++b)
      partial[((size_t)ks * 8 + b) * 6144 + j] = acc[b];
    return;
  }
  const float* in; u16* out; int K, N, lo = 0, hi = 0;
  float scale = 1.0f;
  if (bid < 768)       { in = w_qkv;  out = oq; K = 1024; N = 3072;
                         lo = 1024; hi = 2048; scale = 1.0f / 64.0f; }
  else if (bid < 1024) { in = w_proj; out = op; K = 1024; N = 1024; bid -= 768; }
  else if (bid < 2048) { in = w_mlp1; out = o1; K = 1024; N = 4096; bid -= 1024; }
  else                 { in = w_mlp2; out = o2; K = 4096; N = 1024; bid -= 2048; }
  const int nbx = N >> 6;
  const int n0 = (bid % nbx) * 64, k0 = (bid / nbx) * 64;
  __shared__ u16 t[64][65];
#pragma unroll
  for (int i = 0; i < 16; ++i) {
    int idx = i * 256 + threadIdx.x;
    int r = idx >> 6, cc = idx & 63;
    float v = in[(size_t)(k0 + r) * N + n0 + cc];
    int n = n0 + cc;
    if (n >= lo && n < hi) v *= scale;
    t[r][cc] = f2bf(v);
  }
  __syncthreads();
#pragma unroll
  for (int i = 0; i < 16; ++i) {
    int idx = i * 256 + threadIdx.x;
    int r = idx >> 6, cc = idx & 63;
    out[(size_t)(n0 + r) * K + k0 + cc] = t[cc][r];
  }
}

// ---------------- adaLN stage 2 ----------------
__global__ __launch_bounds__(256)
void adaln_red_k(const float* __restrict__ partial, const float* __restrict__ bias,
                 float* __restrict__ cmod) {
  int g = blockIdx.x * 256 + threadIdx.x;
  int j = g % 6144;
  float s = bias[j];
#pragma unroll 8
  for (int ks = 0; ks < 32; ++ks)
    s += partial[(size_t)ks * 8 * 6144 + g];
  cmod[g] = s;
}

// ---------------- LN + modulate -> bf16 (fp32 input) ----------------
__global__ __launch_bounds__(256)
void lnmod_k(const float* __restrict__ x, const float* __restrict__ cmod,
             int shift_off, int scale_off, u16* __restrict__ out) {
  int row = blockIdx.x;
  int b = row >> 10;
  const float4* xr = (const float4*)(x + (size_t)row * 1024);
  float4 v = xr[threadIdx.x];
  float s = v.x + v.y + v.z + v.w;
  float sq = v.x * v.x + v.y * v.y + v.z * v.z + v.w * v.w;
#pragma unroll
  for (int m = 32; m >= 1; m >>= 1) {
    s  += __shfl_xor(s, m);
    sq += __shfl_xor(sq, m);
  }
  __shared__ float ss[4], ssq[4];
  int wave = threadIdx.x >> 6, lane = threadIdx.x & 63;
  if (lane == 0) { ss[wave] = s; ssq[wave] = sq; }
  __syncthreads();
  s  = ss[0] + ss[1] + ss[2] + ss[3];
  sq = ssq[0] + ssq[1] + ssq[2] + ssq[3];
  float mean = s * (1.f / 1024.f);
  float var  = sq * (1.f / 1024.f) - mean * mean;
  float rstd = rsqrtf(var + 1e-6f);
  int col = threadIdx.x * 4;
  const float* sh = cmod + (size_t)b * 6144 + shift_off + col;
  const float* sc = cmod + (size_t)b * 6144 + scale_off + col;
  float xv[4] = {v.x, v.y, v.z, v.w};
  union { u16 o[4]; uint64_t u; } pk;
#pragma unroll
  for (int j = 0; j < 4; ++j)
    pk.o[j] = f2bf((xv[j] - mean) * rstd * (1.f + sc[j]) + sh[j]);
  *(uint64_t*)(out + (size_t)row * 1024 + col) = pk.u;
}

// ---------------- LN + modulate -> bf16 (bf16 input) ----------------
__global__ __launch_bounds__(256)
void lnmodb_k(const u16* __restrict__ x, const float* __restrict__ cmod,
              int shift_off, int scale_off, u16* __restrict__ out) {
  int row = blockIdx.x;
  int b = row >> 10;
  ushort4 v4 = *(const ushort4*)(x + (size_t)row * 1024 + threadIdx.x * 4);
  float xv[4] = {bf2f(v4.x), bf2f(v4.y), bf2f(v4.z), bf2f(v4.w)};
  float s = xv[0] + xv[1] + xv[2] + xv[3];
  float sq = xv[0]*xv[0] + xv[1]*xv[1] + xv[2]*xv[2] + xv[3]*xv[3];
#pragma unroll
  for (int m = 32; m >= 1; m >>= 1) {
    s  += __shfl_xor(s, m);
    sq += __shfl_xor(sq, m);
  }
  __shared__ float ss[4], ssq[4];
  int wave = threadIdx.x >> 6, lane = threadIdx.x & 63;
  if (lane == 0) { ss[wave] = s; ssq[wave] = sq; }
  __syncthreads();
  s  = ss[0] + ss[1] + ss[2] + ss[3];
  sq = ssq[0] + ssq[1] + ssq[2] + ssq[3];
  float mean = s * (1.f / 1024.f);
  float var  = sq * (1.f / 1024.f) - mean * mean;
  float rstd = rsqrtf(var + 1e-6f);
  int col = threadIdx.x * 4;
  const float* sh = cmod + (size_t)b * 6144 + shift_off + col;
  const float* sc = cmod + (size_t)b * 6144 + scale_off + col;
  union { u16 o[4]; uint64_t u; } pk;
#pragma unroll
  for (int j = 0; j < 4; ++j)
    pk.o[j] = f2bf((xv[j] - mean) * rstd * (1.f + sc[j]) + sh[j]);
  *(uint64_t*)(out + (size_t)row * 1024 + col) = pk.u;
}

// ==== GEMM v11: A-operand DIRECT global->VGPR (L2-served), B via 2-buffer LDS ====
// LDS traffic per block-K-step drops 64KB -> 24KB (stage-writes for A eliminated,
// A fragment reads bypass LDS). Each lane's A-frag is one aligned 16B chunk:
// A[(bm*128 + wr*64 + m*16 + l15)*K + t*32 + lhi*8] — full 64B-line utilization
// (4 lhi-lanes per line). Manual A ping-pong (afA/afB, static names); compiler
// handles vmcnt for A loads. B: same swizzled 2-round gload_lds staging, classic
// 2-buffer barrier (stage(t+1) at iter top, drain covered by 16-MFMA compute).
// EP 0: qkv (cols>=2048 transposed into vt)  EP 1: bias+gelu  EP 2/3: resid+gate.
__device__ __forceinline__ float gelu_f(float x) {
  float z = 1.5957691216057308f * (x + 0.044715f * x * x * x);
  return x / (1.f + __expf(-z));
}

template <int EP>
__global__ __launch_bounds__(256)
void gemm_k(const u16* __restrict__ A, const u16* __restrict__ Bt,
            int N, int K,
            const float* __restrict__ bias, const void* __restrict__ residp,
            const float* __restrict__ gate, void* __restrict__ outp) {
  __shared__ __align__(16) u16 Bs[2][128 * 32];
  const int bn = blockIdx.x, bm = blockIdx.y;
  const int tid = threadIdx.x;
  const int wave = tid >> 6, lane = tid & 63;
  const int l15 = lane & 15, lhi = lane >> 4;
  const int wr = wave >> 1, wc = wave & 1;
  f32x4 acc[4][4] = {};
  const int nkt = K >> 5;                       // even for K = 1024 / 4096
  const size_t arow0 = (size_t)bm * 128;
  const size_t brow0 = (size_t)bn * 128;

  // per-lane A fragment base (row fixed; k advances 32/step)
  const u16* abase[4];
#pragma unroll
  for (int m = 0; m < 4; ++m)
    abase[m] = A + (arow0 + wr * 64 + m * 16 + l15) * (size_t)K + lhi * 8;

  auto stageB = [&](int buf, int kt) {
#pragma unroll
    for (int i = 0; i < 2; ++i) {
      int cch = (i * 4 + wave) * 64 + lane;      // chunk 0..511
      int row = cch >> 2;
      int kc = (cch & 3) ^ ((row >> 1) & 3);     // inverse swizzle on SOURCE
      gload_lds16(Bt + (brow0 + row) * K + (size_t)kt * 32 + kc * 8,
                  &Bs[buf][(i * 4 + wave) * 512]);
    }
  };
  int offB[4];
#pragma unroll
  for (int n = 0; n < 4; ++n) {
    int r = wc * 64 + n * 16 + l15;
    offB[n] = r * 32 + (lhi ^ ((r >> 1) & 3)) * 8;
  }
  auto computeB = [&](int buf, const bf16x8* af) {
    bf16x8 bfr[4];
#pragma unroll
    for (int n = 0; n < 4; ++n) bfr[n] = *(const bf16x8*)&Bs[buf][offB[n]];
#pragma unroll
    for (int m = 0; m < 4; ++m)
#pragma unroll
      for (int n = 0; n < 4; ++n)
        acc[m][n] = MFMA16(af[m], bfr[n], acc[m][n]);
  };

  bf16x8 afA[4], afB[4];
#pragma unroll
  for (int m = 0; m < 4; ++m) afA[m] = *(const bf16x8*)(abase[m]);
  stageB(0, 0);
  __syncthreads();

  for (int t = 0; t < nkt; t += 2) {
    // even half: compute t (afA, Bs[0]); prefetch t+1
    stageB(1, t + 1);                            // t+1 <= nkt-1 always (nkt even)
#pragma unroll
    for (int m = 0; m < 4; ++m)
      afB[m] = *(const bf16x8*)(abase[m] + (t + 1) * 32);
    computeB(0, afA);
    __syncthreads();
    // odd half: compute t+1 (afB, Bs[1]); prefetch t+2
    if (t + 2 < nkt) {
      stageB(0, t + 2);
#pragma unroll
      for (int m = 0; m < 4; ++m)
        afA[m] = *(const bf16x8*)(abase[m] + (t + 2) * 32);
    }
    computeB(1, afB);
    __syncthreads();
  }

#pragma unroll
  for (int m = 0; m < 4; ++m) {
    int row = bm * 128 + wr * 64 + m * 16 + lhi * 4;
#pragma unroll
    for (int n = 0; n < 4; ++n) {
      int col = bn * 128 + wc * 64 + n * 16 + l15;
      if (EP == 0 && col >= 2048) {
        int h = (col - 2048) >> 6, ch = (col - 2048) & 63;
        int b = row >> 10, s0 = row & 1023;
        u16* vt = (u16*)residp;
        union { u16 o[4]; uint64_t u; } pk;
#pragma unroll
        for (int r = 0; r < 4; ++r) pk.o[r] = f2bf(acc[m][n][r]);
        *(uint64_t*)&vt[((size_t)(b * 16 + h) * 64 + ch) * 1024 + s0] = pk.u;
        continue;
      }
#pragma unroll
      for (int r = 0; r < 4; ++r) {
        int rr = row + r;
        float v = acc[m][n][r];
        if (EP == 0) {
          ((u16*)outp)[(size_t)rr * N + col] = f2bf(v);
        } else if (EP == 1) {
          ((u16*)outp)[(size_t)rr * N + col] = f2bf(gelu_f(v + bias[col]));
        } else if (EP == 2) {
          float t2 = v + bias[col];
          int b = rr >> 10;
          float res = ((const float*)residp)[(size_t)rr * N + col];
          ((u16*)outp)[(size_t)rr * N + col] =
              f2bf(res + gate[(size_t)b * 6144 + col] * t2);
        } else {
          float t2 = v + bias[col];
          int b = rr >> 10;
          float res = bf2f(((const u16*)residp)[(size_t)rr * N + col]);
          ((float*)outp)[(size_t)rr * N + col] = res + gate[(size_t)b * 6144 + col] * t2;
        }
      }
    }
  }
}

// ---------------- flash attention (best): QBLK=64, T1 swizzle, fixed-base softmax ----------------
__global__ __launch_bounds__(256)
void attn_k(const u16* __restrict__ qkv, const u16* __restrict__ vt,
            u16* __restrict__ y) {
  int bid0 = blockIdx.x + 16 * (blockIdx.y + 16 * blockIdx.z);
  int swz = (bid0 & 7) * 256 + (bid0 >> 3);
  const int qt = swz & 15, h = (swz >> 4) & 15, b = swz >> 8;
  const int tid = threadIdx.x, wave = tid >> 6, lane = tid & 63;
  const int l15 = lane & 15, lhi = lane >> 4;
  __shared__ __align__(16) u16 Qs[64 * 64];
  __shared__ __align__(16) u16 Ks[2][64 * 64];
  __shared__ __align__(16) u16 Vs[2][64 * 64];
  __shared__ __align__(16) u16 Ps[64 * 64];
  const size_t qrow0 = (size_t)b * 1024 + qt * 64;
  const size_t krow0 = (size_t)b * 1024;
  const size_t vrow0 = (size_t)(b * 16 + h) * 64;

  auto stageQ = [&]() {
#pragma unroll
    for (int i = 0; i < 2; ++i) {
      int c = (i * 4 + wave) * 64 + lane;
      int r = c >> 3, j = (c & 7) ^ (r & 7);
      gload_lds16(qkv + (qrow0 + r) * 3072 + 1024 + h * 64 + j * 8,
                  &Qs[(i * 4 + wave) * 512]);
    }
  };
  auto stageKV = [&](int buf, int kt) {
#pragma unroll
    for (int i = 0; i < 2; ++i) {
      int c = (i * 4 + wave) * 64 + lane;
      int r = c >> 3, j = (c & 7) ^ (r & 7);
      gload_lds16(qkv + (krow0 + kt * 64 + r) * 3072 + h * 64 + j * 8,
                  &Ks[buf][(i * 4 + wave) * 512]);
      gload_lds16(vt + (vrow0 + r) * 1024 + kt * 64 + j * 8,
                  &Vs[buf][(i * 4 + wave) * 512]);
    }
  };
  auto ldb = [](const u16* base, int row, int cc) -> bf16x8 {
    return *(const bf16x8*)&base[row * 64 + ((cc ^ (row & 7)) << 3)];
  };

  stageQ();
  stageKV(0, 0);
  __syncthreads();
  bf16x8 qf[2];
  qf[0] = ldb(Qs, wave * 16 + l15, lhi);
  qf[1] = ldb(Qs, wave * 16 + l15, 4 + lhi);

  bf16x8 ones;
#pragma unroll
  for (int j = 0; j < 8; ++j) ones[j] = (__bf16)1.0f;

  f32x4 o[5] = {};   // o[4] = softmax denominator (ones-column MFMA)

  for (int kt = 0; kt < 16; ++kt) {
    int cur = kt & 1;
    if (kt < 15) stageKV(cur ^ 1, kt + 1);
    f32x4 sf[4] = {};
    __builtin_amdgcn_s_setprio(1);
#pragma unroll
    for (int n = 0; n < 4; ++n) {
      bf16x8 k0 = ldb(Ks[cur], n * 16 + l15, lhi);
      bf16x8 k1 = ldb(Ks[cur], n * 16 + l15, 4 + lhi);
      sf[n] = MFMA16(qf[0], k0, sf[n]);
      sf[n] = MFMA16(qf[1], k1, sf[n]);
    }
    __builtin_amdgcn_s_setprio(0);
    // fixed-base softmax numerator: P = exp(s); no max-reduce, no rescale
#pragma unroll
    for (int r = 0; r < 4; ++r) {
      int row = wave * 16 + lhi * 4 + r;
      int rb = row * 64, sw = (row & 7) << 3;
      Ps[rb + (l15 ^ sw)]        = f2bf(__expf(sf[0][r]));
      Ps[rb + ((l15 + 16) ^ sw)] = f2bf(__expf(sf[1][r]));
      Ps[rb + ((l15 + 32) ^ sw)] = f2bf(__expf(sf[2][r]));
      Ps[rb + ((l15 + 48) ^ sw)] = f2bf(__expf(sf[3][r]));
    }
    // P rows are wave-private: in-wave lgkmcnt (compiler) suffices, no barrier.
    bf16x8 pf0 = ldb(Ps, wave * 16 + l15, lhi);
    bf16x8 pf1 = ldb(Ps, wave * 16 + l15, 4 + lhi);
    __builtin_amdgcn_s_setprio(1);
#pragma unroll
    for (int n = 0; n < 4; ++n) {
      bf16x8 v0 = ldb(Vs[cur], n * 16 + l15, lhi);
      bf16x8 v1 = ldb(Vs[cur], n * 16 + l15, 4 + lhi);
      o[n] = MFMA16(pf0, v0, o[n]);
      o[n] = MFMA16(pf1, v1, o[n]);
    }
    o[4] = MFMA16(pf0, ones, o[4]);
    o[4] = MFMA16(pf1, ones, o[4]);
    __builtin_amdgcn_s_setprio(0);
    __syncthreads();   // single barrier per tile: K/V double-buffer swap guard
  }
#pragma unroll
  for (int r = 0; r < 4; ++r) {
    float inv = 1.0f / o[4][r];
    size_t yrow = (qrow0 + wave * 16 + lhi * 4 + r) * 1024 + h * 64 + l15;
    y[yrow]      = f2bf(o[0][r] * inv);
    y[yrow + 16] = f2bf(o[1][r] * inv);
    y[yrow + 32] = f2bf(o[2][r] * inv);
    y[yrow + 48] = f2bf(o[3][r] * inv);
  }
}

// ---------------- host ----------------
extern "C" void kernel_launch(void* const* d_in, const int* in_sizes, int n_in,
                              void* d_out, int out_size, void* d_ws, size_t ws_size,
                              hipStream_t stream) {
  const float* x      = (const float*)d_in[0];
  const float* c      = (const float*)d_in[1];
  const float* w_ada  = (const float*)d_in[2];
  const float* b_ada  = (const float*)d_in[3];
  const float* w_qkv  = (const float*)d_in[4];
  const float* w_proj = (const float*)d_in[5];
  const float* b_proj = (const float*)d_in[6];
  const float* w_mlp1 = (const float*)d_in[7];
  const float* b_mlp1 = (const float*)d_in[8];
  const float* w_mlp2 = (const float*)d_in[9];
  const float* b_mlp2 = (const float*)d_in[10];
  float* out = (float*)d_out;

  char* ws = (char*)d_ws;
  size_t off = 0;
  auto alloc = [&](size_t bytes) {
    void* p = ws + off;
    off += (bytes + 255) & ~(size_t)255;
    return p;
  };
  float* cmod  = (float*)alloc((size_t)8 * 6144 * 4);
  float* apart = (float*)alloc((size_t)32 * 8 * 6144 * 4);
  u16* wqkvT   = (u16*)alloc((size_t)3072 * 1024 * 2);
  u16* wprojT  = (u16*)alloc((size_t)1024 * 1024 * 2);
  u16* wmlp1T  = (u16*)alloc((size_t)4096 * 1024 * 2);
  u16* wmlp2T  = (u16*)alloc((size_t)1024 * 4096 * 2);
  u16* xmod    = (u16*)alloc((size_t)8192 * 1024 * 2);   // reused as attention out y
  u16* qkv     = (u16*)alloc((size_t)8192 * 3072 * 2);   // front reused as x_mod2
  u16* vt      = (u16*)alloc((size_t)8 * 16 * 64 * 1024 * 2);
  u16* x1      = (u16*)alloc((size_t)8192 * 1024 * 2);   // residual stream, bf16
  u16* hbuf    = (u16*)alloc((size_t)8192 * 4096 * 2);
  u16* ybuf  = xmod;   // x_mod dead after qkv GEMM
  u16* xmod2 = qkv;    // qkv dead after attention

  prep_k<<<3840, 256, 0, stream>>>(w_qkv, w_proj, w_mlp1, w_mlp2,
                                   wqkvT, wprojT, wmlp1T, wmlp2T,
                                   c, w_ada, apart);
  adaln_red_k<<<192, 256, 0, stream>>>(apart, b_ada, cmod);
  lnmod_k<<<8192, 256, 0, stream>>>(x, cmod, 0, 1024, xmod);
  gemm_k<0><<<dim3(3072 / 128, 8192 / 128), 256, 0, stream>>>(
      xmod, wqkvT, 3072, 1024, nullptr, vt, nullptr, qkv);   // V fused-transposed into vt
  attn_k<<<dim3(16, 16, 8), 256, 0, stream>>>(qkv, vt, ybuf);
  gemm_k<2><<<dim3(1024 / 128, 8192 / 128), 256, 0, stream>>>(
      ybuf, wprojT, 1024, 1024, b_proj, x, cmod + 2048, x1);
  lnmodb_k<<<8192, 256, 0, stream>>>(x1, cmod, 3072, 4096, xmod2);
  gemm_k<1><<<dim3(4096 / 128, 8192 / 128), 256, 0, stream>>>(
      xmod2, wmlp1T, 4096, 1024, b_mlp1, nullptr, nullptr, hbuf);
  gemm_k<3><<<dim3(1024 / 128, 8192 / 128), 256, 0, stream>>>(
      hbuf, wmlp2T, 1024, 4096, b_mlp2, x1, cmod + 5120, out);
}

// Round 19
// 388.420 us; speedup vs baseline: 1.5944x; 1.5944x over previous
//
#include <hip/hip_runtime.h>
#include <stdint.h>

typedef unsigned short u16;
using bf16x8 = __attribute__((ext_vector_type(8))) __bf16;
using f32x4  = __attribute__((ext_vector_type(4))) float;

#define MFMA16(a,b,c) __builtin_amdgcn_mfma_f32_16x16x32_bf16((a),(b),(c),0,0,0)

__device__ __forceinline__ u16 f2bf(float f) {
  union { float f; uint32_t u; } v; v.f = f;
  uint32_t r = v.u + 0x7FFFu + ((v.u >> 16) & 1u);
  return (u16)(r >> 16);
}
__device__ __forceinline__ float bf2f(u16 u) {
  union { uint32_t u; float f; } v; v.u = ((uint32_t)u) << 16;
  return v.f;
}

// async global->LDS, 16B per lane; lds ptr must be wave-uniform (HW: base + lane*16)
__device__ __forceinline__ void gload_lds16(const void* g, void* l) {
  typedef const __attribute__((address_space(1))) void* gp_t;
  typedef __attribute__((address_space(3))) void* lp_t;
  __builtin_amdgcn_global_load_lds((gp_t)(uintptr_t)g,
                                   (lp_t)(uint32_t)(uintptr_t)l, 16, 0, 0);
}

// ==== prep_k: fused {4x weight cast+transpose} + {adaLN stage 1} ====
__global__ __launch_bounds__(256)
void prep_k(const float* __restrict__ w_qkv, const float* __restrict__ w_proj,
            const float* __restrict__ w_mlp1, const float* __restrict__ w_mlp2,
            u16* __restrict__ oq, u16* __restrict__ op,
            u16* __restrict__ o1, u16* __restrict__ o2,
            const float* __restrict__ c, const float* __restrict__ w_ada,
            float* __restrict__ partial) {
  int bid = blockIdx.x;
  if (bid >= 3072) {
    bid -= 3072;
    const int jb = bid % 24, ks = bid / 24;
    const int j = jb * 256 + threadIdx.x;
    __shared__ float sil[8][32];
    {
      int b = threadIdx.x >> 5, kk = threadIdx.x & 31;
      float v = c[b * 1024 + ks * 32 + kk];
      sil[b][kk] = v / (1.f + __expf(-v));
    }
    __syncthreads();
    float acc[8] = {0,0,0,0,0,0,0,0};
#pragma unroll 8
    for (int kk = 0; kk < 32; ++kk) {
      float wv = w_ada[(size_t)(ks * 32 + kk) * 6144 + j];
#pragma unroll
      for (int b = 0; b < 8; ++b) acc[b] += sil[b][kk] * wv;
    }
#pragma unroll
    for (int b = 0; b < 8; ++b)
      partial[((size_t)ks * 8 + b) * 6144 + j] = acc[b];
    return;
  }
  const float* in; u16* out; int K, N, lo = 0, hi = 0;
  float scale = 1.0f;
  if (bid < 768)       { in = w_qkv;  out = oq; K = 1024; N = 3072;
                         lo = 1024; hi = 2048; scale = 1.0f / 64.0f; }
  else if (bid < 1024) { in = w_proj; out = op; K = 1024; N = 1024; bid -= 768; }
  else if (bid < 2048) { in = w_mlp1; out = o1; K = 1024; N = 4096; bid -= 1024; }
  else                 { in = w_mlp2; out = o2; K = 4096; N = 1024; bid -= 2048; }
  const int nbx = N >> 6;
  const int n0 = (bid % nbx) * 64, k0 = (bid / nbx) * 64;
  __shared__ u16 t[64][65];
#pragma unroll
  for (int i = 0; i < 16; ++i) {
    int idx = i * 256 + threadIdx.x;
    int r = idx >> 6, cc = idx & 63;
    float v = in[(size_t)(k0 + r) * N + n0 + cc];
    int n = n0 + cc;
    if (n >= lo && n < hi) v *= scale;
    t[r][cc] = f2bf(v);
  }
  __syncthreads();
#pragma unroll
  for (int i = 0; i < 16; ++i) {
    int idx = i * 256 + threadIdx.x;
    int r = idx >> 6, cc = idx & 63;
    out[(size_t)(n0 + r) * K + k0 + cc] = t[cc][r];
  }
}

// ---------------- adaLN stage 2 ----------------
__global__ __launch_bounds__(256)
void adaln_red_k(const float* __restrict__ partial, const float* __restrict__ bias,
                 float* __restrict__ cmod) {
  int g = blockIdx.x * 256 + threadIdx.x;
  int j = g % 6144;
  float s = bias[j];
#pragma unroll 8
  for (int ks = 0; ks < 32; ++ks)
    s += partial[(size_t)ks * 8 * 6144 + g];
  cmod[g] = s;
}

// ---------------- LN + modulate -> bf16 (fp32 input) ----------------
__global__ __launch_bounds__(256)
void lnmod_k(const float* __restrict__ x, const float* __restrict__ cmod,
             int shift_off, int scale_off, u16* __restrict__ out) {
  int row = blockIdx.x;
  int b = row >> 10;
  const float4* xr = (const float4*)(x + (size_t)row * 1024);
  float4 v = xr[threadIdx.x];
  float s = v.x + v.y + v.z + v.w;
  float sq = v.x * v.x + v.y * v.y + v.z * v.z + v.w * v.w;
#pragma unroll
  for (int m = 32; m >= 1; m >>= 1) {
    s  += __shfl_xor(s, m);
    sq += __shfl_xor(sq, m);
  }
  __shared__ float ss[4], ssq[4];
  int wave = threadIdx.x >> 6, lane = threadIdx.x & 63;
  if (lane == 0) { ss[wave] = s; ssq[wave] = sq; }
  __syncthreads();
  s  = ss[0] + ss[1] + ss[2] + ss[3];
  sq = ssq[0] + ssq[1] + ssq[2] + ssq[3];
  float mean = s * (1.f / 1024.f);
  float var  = sq * (1.f / 1024.f) - mean * mean;
  float rstd = rsqrtf(var + 1e-6f);
  int col = threadIdx.x * 4;
  const float* sh = cmod + (size_t)b * 6144 + shift_off + col;
  const float* sc = cmod + (size_t)b * 6144 + scale_off + col;
  float xv[4] = {v.x, v.y, v.z, v.w};
  union { u16 o[4]; uint64_t u; } pk;
#pragma unroll
  for (int j = 0; j < 4; ++j)
    pk.o[j] = f2bf((xv[j] - mean) * rstd * (1.f + sc[j]) + sh[j]);
  *(uint64_t*)(out + (size_t)row * 1024 + col) = pk.u;
}

// ---------------- LN + modulate -> bf16 (bf16 input) ----------------
__global__ __launch_bounds__(256)
void lnmodb_k(const u16* __restrict__ x, const float* __restrict__ cmod,
              int shift_off, int scale_off, u16* __restrict__ out) {
  int row = blockIdx.x;
  int b = row >> 10;
  ushort4 v4 = *(const ushort4*)(x + (size_t)row * 1024 + threadIdx.x * 4);
  float xv[4] = {bf2f(v4.x), bf2f(v4.y), bf2f(v4.z), bf2f(v4.w)};
  float s = xv[0] + xv[1] + xv[2] + xv[3];
  float sq = xv[0]*xv[0] + xv[1]*xv[1] + xv[2]*xv[2] + xv[3]*xv[3];
#pragma unroll
  for (int m = 32; m >= 1; m >>= 1) {
    s  += __shfl_xor(s, m);
    sq += __shfl_xor(sq, m);
  }
  __shared__ float ss[4], ssq[4];
  int wave = threadIdx.x >> 6, lane = threadIdx.x & 63;
  if (lane == 0) { ss[wave] = s; ssq[wave] = sq; }
  __syncthreads();
  s  = ss[0] + ss[1] + ss[2] + ss[3];
  sq = ssq[0] + ssq[1] + ssq[2] + ssq[3];
  float mean = s * (1.f / 1024.f);
  float var  = sq * (1.f / 1024.f) - mean * mean;
  float rstd = rsqrtf(var + 1e-6f);
  int col = threadIdx.x * 4;
  const float* sh = cmod + (size_t)b * 6144 + shift_off + col;
  const float* sc = cmod + (size_t)b * 6144 + scale_off + col;
  union { u16 o[4]; uint64_t u; } pk;
#pragma unroll
  for (int j = 0; j < 4; ++j)
    pk.o[j] = f2bf((xv[j] - mean) * rstd * (1.f + sc[j]) + sh[j]);
  *(uint64_t*)(out + (size_t)row * 1024 + col) = pk.u;
}

// ==== GEMM v10 (measured best): 3-buffer counted-vmcnt(4), 128x128, BK=32 ====
// EP 0: qkv fused epilogue — cols<2048 -> qkv buffer; cols>=2048 (V) transposed into vt.
// EP 1: bias+gelu -> bf16 (mlp1)
// EP 2: bias + resid(fp32) + gate -> bf16 (proj -> x1 bf16)
// EP 3: bias + resid(bf16) + gate -> fp32 (mlp2 -> out)
__device__ __forceinline__ float gelu_f(float x) {
  float z = 1.5957691216057308f * (x + 0.044715f * x * x * x);
  return x / (1.f + __expf(-z));
}

template <int EP>
__global__ __launch_bounds__(256)
void gemm_k(const u16* __restrict__ A, const u16* __restrict__ Bt,
            int N, int K,
            const float* __restrict__ bias, const void* __restrict__ residp,
            const float* __restrict__ gate, void* __restrict__ outp) {
  __shared__ __align__(16) u16 lds[3][2][128 * 32];
  const int bn = blockIdx.x, bm = blockIdx.y;
  const int tid = threadIdx.x;
  const int wave = tid >> 6, lane = tid & 63;
  const int l15 = lane & 15, lhi = lane >> 4;
  const int wr = wave >> 1, wc = wave & 1;
  f32x4 acc[4][4] = {};
  const int nkt = K >> 5;
  const size_t arow0 = (size_t)bm * 128;
  const size_t brow0 = (size_t)bn * 128;

  auto stage = [&](int buf, int kt) {
#pragma unroll
    for (int i = 0; i < 2; ++i) {
      int c = (i * 4 + wave) * 64 + lane;
      int row = c >> 2;
      int kc = (c & 3) ^ ((row >> 1) & 3);     // inverse swizzle on SOURCE (rule 21)
      gload_lds16(A  + (arow0 + row) * K + (size_t)kt * 32 + kc * 8,
                  &lds[buf][0][(i * 4 + wave) * 512]);
      gload_lds16(Bt + (brow0 + row) * K + (size_t)kt * 32 + kc * 8,
                  &lds[buf][1][(i * 4 + wave) * 512]);
    }
  };
  auto compute = [&](int buf) {
    bf16x8 af[4], bfr[4];
#pragma unroll
    for (int m = 0; m < 4; ++m) {
      int r = wr * 64 + m * 16 + l15;
      af[m] = *(const bf16x8*)&lds[buf][0][r * 32 + (lhi ^ ((r >> 1) & 3)) * 8];
    }
#pragma unroll
    for (int n = 0; n < 4; ++n) {
      int r = wc * 64 + n * 16 + l15;
      bfr[n] = *(const bf16x8*)&lds[buf][1][r * 32 + (lhi ^ ((r >> 1) & 3)) * 8];
    }
#pragma unroll
    for (int m = 0; m < 4; ++m)
#pragma unroll
      for (int n = 0; n < 4; ++n)
        acc[m][n] = MFMA16(af[m], bfr[n], acc[m][n]);
  };

  // prologue: stage tiles 0,1 (8 vmem/lane); wait tile 0 (4 left in flight)
  stage(0, 0);
  stage(1, 1);
  asm volatile("s_waitcnt vmcnt(4)" ::: "memory");
  __builtin_amdgcn_s_barrier();
  asm volatile("" ::: "memory");

  for (int t = 0; t < nkt; ++t) {
    const int cur = t % 3;
    const bool pf2 = (t + 2 < nkt);
    if (pf2) stage((t + 2) % 3, t + 2);        // overlaps with compute below
    compute(cur);
    if (t + 1 < nkt) {
      if (pf2) asm volatile("s_waitcnt vmcnt(4)" ::: "memory");
      else     asm volatile("s_waitcnt vmcnt(0)" ::: "memory");
      __builtin_amdgcn_s_barrier();
      asm volatile("" ::: "memory");
    }
  }

#pragma unroll
  for (int m = 0; m < 4; ++m) {
    int row = bm * 128 + wr * 64 + m * 16 + lhi * 4;
#pragma unroll
    for (int n = 0; n < 4; ++n) {
      int col = bn * 128 + wc * 64 + n * 16 + l15;
      if (EP == 0 && col >= 2048) {
        // V-section: write transposed into vt[((b*16+h)*64+ch)*1024 + s], 4 s at once
        int h = (col - 2048) >> 6, ch = (col - 2048) & 63;
        int b = row >> 10, s0 = row & 1023;     // 4-aligned, no 1024 crossing
        u16* vt = (u16*)residp;
        union { u16 o[4]; uint64_t u; } pk;
#pragma unroll
        for (int r = 0; r < 4; ++r) pk.o[r] = f2bf(acc[m][n][r]);
        *(uint64_t*)&vt[((size_t)(b * 16 + h) * 64 + ch) * 1024 + s0] = pk.u;
        continue;
      }
#pragma unroll
      for (int r = 0; r < 4; ++r) {
        int rr = row + r;
        float v = acc[m][n][r];
        if (EP == 0) {
          ((u16*)outp)[(size_t)rr * N + col] = f2bf(v);
        } else if (EP == 1) {
          ((u16*)outp)[(size_t)rr * N + col] = f2bf(gelu_f(v + bias[col]));
        } else if (EP == 2) {
          float t2 = v + bias[col];
          int b = rr >> 10;
          float res = ((const float*)residp)[(size_t)rr * N + col];
          ((u16*)outp)[(size_t)rr * N + col] =
              f2bf(res + gate[(size_t)b * 6144 + col] * t2);
        } else {
          float t2 = v + bias[col];
          int b = rr >> 10;
          float res = bf2f(((const u16*)residp)[(size_t)rr * N + col]);
          ((float*)outp)[(size_t)rr * N + col] = res + gate[(size_t)b * 6144 + col] * t2;
        }
      }
    }
  }
}

// ---------------- flash attention (best): QBLK=64, T1 swizzle, fixed-base softmax ----------------
__global__ __launch_bounds__(256)
void attn_k(const u16* __restrict__ qkv, const u16* __restrict__ vt,
            u16* __restrict__ y) {
  int bid0 = blockIdx.x + 16 * (blockIdx.y + 16 * blockIdx.z);
  int swz = (bid0 & 7) * 256 + (bid0 >> 3);
  const int qt = swz & 15, h = (swz >> 4) & 15, b = swz >> 8;
  const int tid = threadIdx.x, wave = tid >> 6, lane = tid & 63;
  const int l15 = lane & 15, lhi = lane >> 4;
  __shared__ __align__(16) u16 Qs[64 * 64];
  __shared__ __align__(16) u16 Ks[2][64 * 64];
  __shared__ __align__(16) u16 Vs[2][64 * 64];
  __shared__ __align__(16) u16 Ps[64 * 64];
  const size_t qrow0 = (size_t)b * 1024 + qt * 64;
  const size_t krow0 = (size_t)b * 1024;
  const size_t vrow0 = (size_t)(b * 16 + h) * 64;

  auto stageQ = [&]() {
#pragma unroll
    for (int i = 0; i < 2; ++i) {
      int c = (i * 4 + wave) * 64 + lane;
      int r = c >> 3, j = (c & 7) ^ (r & 7);
      gload_lds16(qkv + (qrow0 + r) * 3072 + 1024 + h * 64 + j * 8,
                  &Qs[(i * 4 + wave) * 512]);
    }
  };
  auto stageKV = [&](int buf, int kt) {
#pragma unroll
    for (int i = 0; i < 2; ++i) {
      int c = (i * 4 + wave) * 64 + lane;
      int r = c >> 3, j = (c & 7) ^ (r & 7);
      gload_lds16(qkv + (krow0 + kt * 64 + r) * 3072 + h * 64 + j * 8,
                  &Ks[buf][(i * 4 + wave) * 512]);
      gload_lds16(vt + (vrow0 + r) * 1024 + kt * 64 + j * 8,
                  &Vs[buf][(i * 4 + wave) * 512]);
    }
  };
  auto ldb = [](const u16* base, int row, int cc) -> bf16x8 {
    return *(const bf16x8*)&base[row * 64 + ((cc ^ (row & 7)) << 3)];
  };

  stageQ();
  stageKV(0, 0);
  __syncthreads();
  bf16x8 qf[2];
  qf[0] = ldb(Qs, wave * 16 + l15, lhi);
  qf[1] = ldb(Qs, wave * 16 + l15, 4 + lhi);

  bf16x8 ones;
#pragma unroll
  for (int j = 0; j < 8; ++j) ones[j] = (__bf16)1.0f;

  f32x4 o[5] = {};   // o[4] = softmax denominator (ones-column MFMA)

  for (int kt = 0; kt < 16; ++kt) {
    int cur = kt & 1;
    if (kt < 15) stageKV(cur ^ 1, kt + 1);
    f32x4 sf[4] = {};
    __builtin_amdgcn_s_setprio(1);
#pragma unroll
    for (int n = 0; n < 4; ++n) {
      bf16x8 k0 = ldb(Ks[cur], n * 16 + l15, lhi);
      bf16x8 k1 = ldb(Ks[cur], n * 16 + l15, 4 + lhi);
      sf[n] = MFMA16(qf[0], k0, sf[n]);
      sf[n] = MFMA16(qf[1], k1, sf[n]);
    }
    __builtin_amdgcn_s_setprio(0);
    // fixed-base softmax numerator: P = exp(s); no max-reduce, no rescale
#pragma unroll
    for (int r = 0; r < 4; ++r) {
      int row = wave * 16 + lhi * 4 + r;
      int rb = row * 64, sw = (row & 7) << 3;
      Ps[rb + (l15 ^ sw)]        = f2bf(__expf(sf[0][r]));
      Ps[rb + ((l15 + 16) ^ sw)] = f2bf(__expf(sf[1][r]));
      Ps[rb + ((l15 + 32) ^ sw)] = f2bf(__expf(sf[2][r]));
      Ps[rb + ((l15 + 48) ^ sw)] = f2bf(__expf(sf[3][r]));
    }
    // P rows are wave-private: in-wave lgkmcnt (compiler) suffices, no barrier.
    bf16x8 pf0 = ldb(Ps, wave * 16 + l15, lhi);
    bf16x8 pf1 = ldb(Ps, wave * 16 + l15, 4 + lhi);
    __builtin_amdgcn_s_setprio(1);
#pragma unroll
    for (int n = 0; n < 4; ++n) {
      bf16x8 v0 = ldb(Vs[cur], n * 16 + l15, lhi);
      bf16x8 v1 = ldb(Vs[cur], n * 16 + l15, 4 + lhi);
      o[n] = MFMA16(pf0, v0, o[n]);
      o[n] = MFMA16(pf1, v1, o[n]);
    }
    o[4] = MFMA16(pf0, ones, o[4]);
    o[4] = MFMA16(pf1, ones, o[4]);
    __builtin_amdgcn_s_setprio(0);
    __syncthreads();   // single barrier per tile: K/V double-buffer swap guard
  }
#pragma unroll
  for (int r = 0; r < 4; ++r) {
    float inv = 1.0f / o[4][r];
    size_t yrow = (qrow0 + wave * 16 + lhi * 4 + r) * 1024 + h * 64 + l15;
    y[yrow]      = f2bf(o[0][r] * inv);
    y[yrow + 16] = f2bf(o[1][r] * inv);
    y[yrow + 32] = f2bf(o[2][r] * inv);
    y[yrow + 48] = f2bf(o[3][r] * inv);
  }
}

// ---------------- host ----------------
extern "C" void kernel_launch(void* const* d_in, const int* in_sizes, int n_in,
                              void* d_out, int out_size, void* d_ws, size_t ws_size,
                              hipStream_t stream) {
  const float* x      = (const float*)d_in[0];
  const float* c      = (const float*)d_in[1];
  const float* w_ada  = (const float*)d_in[2];
  const float* b_ada  = (const float*)d_in[3];
  const float* w_qkv  = (const float*)d_in[4];
  const float* w_proj = (const float*)d_in[5];
  const float* b_proj = (const float*)d_in[6];
  const float* w_mlp1 = (const float*)d_in[7];
  const float* b_mlp1 = (const float*)d_in[8];
  const float* w_mlp2 = (const float*)d_in[9];
  const float* b_mlp2 = (const float*)d_in[10];
  float* out = (float*)d_out;

  char* ws = (char*)d_ws;
  size_t off = 0;
  auto alloc = [&](size_t bytes) {
    void* p = ws + off;
    off += (bytes + 255) & ~(size_t)255;
    return p;
  };
  float* cmod  = (float*)alloc((size_t)8 * 6144 * 4);
  float* apart = (float*)alloc((size_t)32 * 8 * 6144 * 4);
  u16* wqkvT   = (u16*)alloc((size_t)3072 * 1024 * 2);
  u16* wprojT  = (u16*)alloc((size_t)1024 * 1024 * 2);
  u16* wmlp1T  = (u16*)alloc((size_t)4096 * 1024 * 2);
  u16* wmlp2T  = (u16*)alloc((size_t)1024 * 4096 * 2);
  u16* xmod    = (u16*)alloc((size_t)8192 * 1024 * 2);   // reused as attention out y
  u16* qkv     = (u16*)alloc((size_t)8192 * 3072 * 2);   // front reused as x_mod2
  u16* vt      = (u16*)alloc((size_t)8 * 16 * 64 * 1024 * 2);
  u16* x1      = (u16*)alloc((size_t)8192 * 1024 * 2);   // residual stream, bf16
  u16* hbuf    = (u16*)alloc((size_t)8192 * 4096 * 2);
  u16* ybuf  = xmod;   // x_mod dead after qkv GEMM
  u16* xmod2 = qkv;    // qkv dead after attention

  prep_k<<<3840, 256, 0, stream>>>(w_qkv, w_proj, w_mlp1, w_mlp2,
                                   wqkvT, wprojT, wmlp1T, wmlp2T,
                                   c, w_ada, apart);
  adaln_red_k<<<192, 256, 0, stream>>>(apart, b_ada, cmod);
  lnmod_k<<<8192, 256, 0, stream>>>(x, cmod, 0, 1024, xmod);
  gemm_k<0><<<dim3(3072 / 128, 8192 / 128), 256, 0, stream>>>(
      xmod, wqkvT, 3072, 1024, nullptr, vt, nullptr, qkv);   // V fused-transposed into vt
  attn_k<<<dim3(16, 16, 8), 256, 0, stream>>>(qkv, vt, ybuf);
  gemm_k<2><<<dim3(1024 / 128, 8192 / 128), 256, 0, stream>>>(
      ybuf, wprojT, 1024, 1024, b_proj, x, cmod + 2048, x1);
  lnmodb_k<<<8192, 256, 0, stream>>>(x1, cmod, 3072, 4096, xmod2);
  gemm_k<1><<<dim3(4096 / 128, 8192 / 128), 256, 0, stream>>>(
      xmod2, wmlp1T, 4096, 1024, b_mlp1, nullptr, nullptr, hbuf);
  gemm_k<3><<<dim3(1024 / 128, 8192 / 128), 256, 0, stream>>>(
      hbuf, wmlp2T, 1024, 4096, b_mlp2, x1, cmod + 5120, out);
}

// Round 20
// 374.026 us; speedup vs baseline: 1.6557x; 1.0385x over previous
//
#include <hip/hip_runtime.h>
#include <stdint.h>

typedef unsigned short u16;
using bf16x8 = __attribute__((ext_vector_type(8))) __bf16;
using f32x4  = __attribute__((ext_vector_type(4))) float;

#define MFMA16(a,b,c) __builtin_amdgcn_mfma_f32_16x16x32_bf16((a),(b),(c),0,0,0)

__device__ __forceinline__ u16 f2bf(float f) {
  union { float f; uint32_t u; } v; v.f = f;
  uint32_t r = v.u + 0x7FFFu + ((v.u >> 16) & 1u);
  return (u16)(r >> 16);
}
__device__ __forceinline__ float bf2f(u16 u) {
  union { uint32_t u; float f; } v; v.u = ((uint32_t)u) << 16;
  return v.f;
}

// async global->LDS, 16B per lane; lds ptr must be wave-uniform (HW: base + lane*16)
__device__ __forceinline__ void gload_lds16(const void* g, void* l) {
  typedef const __attribute__((address_space(1))) void* gp_t;
  typedef __attribute__((address_space(3))) void* lp_t;
  __builtin_amdgcn_global_load_lds((gp_t)(uintptr_t)g,
                                   (lp_t)(uint32_t)(uintptr_t)l, 16, 0, 0);
}

// ==== prep_k: fused {4x weight cast+transpose} + {adaLN stage 1} ====
__global__ __launch_bounds__(256)
void prep_k(const float* __restrict__ w_qkv, const float* __restrict__ w_proj,
            const float* __restrict__ w_mlp1, const float* __restrict__ w_mlp2,
            u16* __restrict__ oq, u16* __restrict__ op,
            u16* __restrict__ o1, u16* __restrict__ o2,
            const float* __restrict__ c, const float* __restrict__ w_ada,
            float* __restrict__ partial) {
  int bid = blockIdx.x;
  if (bid >= 3072) {
    bid -= 3072;
    const int jb = bid % 24, ks = bid / 24;
    const int j = jb * 256 + threadIdx.x;
    __shared__ float sil[8][32];
    {
      int b = threadIdx.x >> 5, kk = threadIdx.x & 31;
      float v = c[b * 1024 + ks * 32 + kk];
      sil[b][kk] = v / (1.f + __expf(-v));
    }
    __syncthreads();
    float acc[8] = {0,0,0,0,0,0,0,0};
#pragma unroll 8
    for (int kk = 0; kk < 32; ++kk) {
      float wv = w_ada[(size_t)(ks * 32 + kk) * 6144 + j];
#pragma unroll
      for (int b = 0; b < 8; ++b) acc[b] += sil[b][kk] * wv;
    }
#pragma unroll
    for (int b = 0; b < 8; ++b)
      partial[((size_t)ks * 8 + b) * 6144 + j] = acc[b];
    return;
  }
  const float* in; u16* out; int K, N, lo = 0, hi = 0;
  float scale = 1.0f;
  if (bid < 768)       { in = w_qkv;  out = oq; K = 1024; N = 3072;
                         lo = 1024; hi = 2048; scale = 1.0f / 64.0f; }
  else if (bid < 1024) { in = w_proj; out = op; K = 1024; N = 1024; bid -= 768; }
  else if (bid < 2048) { in = w_mlp1; out = o1; K = 1024; N = 4096; bid -= 1024; }
  else                 { in = w_mlp2; out = o2; K = 4096; N = 1024; bid -= 2048; }
  const int nbx = N >> 6;
  const int n0 = (bid % nbx) * 64, k0 = (bid / nbx) * 64;
  __shared__ u16 t[64][65];
#pragma unroll
  for (int i = 0; i < 16; ++i) {
    int idx = i * 256 + threadIdx.x;
    int r = idx >> 6, cc = idx & 63;
    float v = in[(size_t)(k0 + r) * N + n0 + cc];
    int n = n0 + cc;
    if (n >= lo && n < hi) v *= scale;
    t[r][cc] = f2bf(v);
  }
  __syncthreads();
#pragma unroll
  for (int i = 0; i < 16; ++i) {
    int idx = i * 256 + threadIdx.x;
    int r = idx >> 6, cc = idx & 63;
    out[(size_t)(n0 + r) * K + k0 + cc] = t[cc][r];
  }
}

// ---------------- adaLN stage 2 ----------------
__global__ __launch_bounds__(256)
void adaln_red_k(const float* __restrict__ partial, const float* __restrict__ bias,
                 float* __restrict__ cmod) {
  int g = blockIdx.x * 256 + threadIdx.x;
  int j = g % 6144;
  float s = bias[j];
#pragma unroll 8
  for (int ks = 0; ks < 32; ++ks)
    s += partial[(size_t)ks * 8 * 6144 + g];
  cmod[g] = s;
}

// ---------------- LN + modulate -> bf16 (fp32 input) ----------------
__global__ __launch_bounds__(256)
void lnmod_k(const float* __restrict__ x, const float* __restrict__ cmod,
             int shift_off, int scale_off, u16* __restrict__ out) {
  int row = blockIdx.x;
  int b = row >> 10;
  const float4* xr = (const float4*)(x + (size_t)row * 1024);
  float4 v = xr[threadIdx.x];
  float s = v.x + v.y + v.z + v.w;
  float sq = v.x * v.x + v.y * v.y + v.z * v.z + v.w * v.w;
#pragma unroll
  for (int m = 32; m >= 1; m >>= 1) {
    s  += __shfl_xor(s, m);
    sq += __shfl_xor(sq, m);
  }
  __shared__ float ss[4], ssq[4];
  int wave = threadIdx.x >> 6, lane = threadIdx.x & 63;
  if (lane == 0) { ss[wave] = s; ssq[wave] = sq; }
  __syncthreads();
  s  = ss[0] + ss[1] + ss[2] + ss[3];
  sq = ssq[0] + ssq[1] + ssq[2] + ssq[3];
  float mean = s * (1.f / 1024.f);
  float var  = sq * (1.f / 1024.f) - mean * mean;
  float rstd = rsqrtf(var + 1e-6f);
  int col = threadIdx.x * 4;
  const float* sh = cmod + (size_t)b * 6144 + shift_off + col;
  const float* sc = cmod + (size_t)b * 6144 + scale_off + col;
  float xv[4] = {v.x, v.y, v.z, v.w};
  union { u16 o[4]; uint64_t u; } pk;
#pragma unroll
  for (int j = 0; j < 4; ++j)
    pk.o[j] = f2bf((xv[j] - mean) * rstd * (1.f + sc[j]) + sh[j]);
  *(uint64_t*)(out + (size_t)row * 1024 + col) = pk.u;
}

// ---------------- LN + modulate -> bf16 (bf16 input) ----------------
__global__ __launch_bounds__(256)
void lnmodb_k(const u16* __restrict__ x, const float* __restrict__ cmod,
              int shift_off, int scale_off, u16* __restrict__ out) {
  int row = blockIdx.x;
  int b = row >> 10;
  ushort4 v4 = *(const ushort4*)(x + (size_t)row * 1024 + threadIdx.x * 4);
  float xv[4] = {bf2f(v4.x), bf2f(v4.y), bf2f(v4.z), bf2f(v4.w)};
  float s = xv[0] + xv[1] + xv[2] + xv[3];
  float sq = xv[0]*xv[0] + xv[1]*xv[1] + xv[2]*xv[2] + xv[3]*xv[3];
#pragma unroll
  for (int m = 32; m >= 1; m >>= 1) {
    s  += __shfl_xor(s, m);
    sq += __shfl_xor(sq, m);
  }
  __shared__ float ss[4], ssq[4];
  int wave = threadIdx.x >> 6, lane = threadIdx.x & 63;
  if (lane == 0) { ss[wave] = s; ssq[wave] = sq; }
  __syncthreads();
  s  = ss[0] + ss[1] + ss[2] + ss[3];
  sq = ssq[0] + ssq[1] + ssq[2] + ssq[3];
  float mean = s * (1.f / 1024.f);
  float var  = sq * (1.f / 1024.f) - mean * mean;
  float rstd = rsqrtf(var + 1e-6f);
  int col = threadIdx.x * 4;
  const float* sh = cmod + (size_t)b * 6144 + shift_off + col;
  const float* sc = cmod + (size_t)b * 6144 + scale_off + col;
  union { u16 o[4]; uint64_t u; } pk;
#pragma unroll
  for (int j = 0; j < 4; ++j)
    pk.o[j] = f2bf((xv[j] - mean) * rstd * (1.f + sc[j]) + sh[j]);
  *(uint64_t*)(out + (size_t)row * 1024 + col) = pk.u;
}

// ==== GEMM v10 (measured best): 3-buffer counted-vmcnt(4), 128x128, BK=32 ====
__device__ __forceinline__ float gelu_f(float x) {
  float z = 1.5957691216057308f * (x + 0.044715f * x * x * x);
  return x / (1.f + __expf(-z));
}

template <int EP>
__global__ __launch_bounds__(256)
void gemm_k(const u16* __restrict__ A, const u16* __restrict__ Bt,
            int N, int K,
            const float* __restrict__ bias, const void* __restrict__ residp,
            const float* __restrict__ gate, void* __restrict__ outp) {
  __shared__ __align__(16) u16 lds[3][2][128 * 32];
  const int bn = blockIdx.x, bm = blockIdx.y;
  const int tid = threadIdx.x;
  const int wave = tid >> 6, lane = tid & 63;
  const int l15 = lane & 15, lhi = lane >> 4;
  const int wr = wave >> 1, wc = wave & 1;
  f32x4 acc[4][4] = {};
  const int nkt = K >> 5;
  const size_t arow0 = (size_t)bm * 128;
  const size_t brow0 = (size_t)bn * 128;

  auto stage = [&](int buf, int kt) {
#pragma unroll
    for (int i = 0; i < 2; ++i) {
      int c = (i * 4 + wave) * 64 + lane;
      int row = c >> 2;
      int kc = (c & 3) ^ ((row >> 1) & 3);
      gload_lds16(A  + (arow0 + row) * K + (size_t)kt * 32 + kc * 8,
                  &lds[buf][0][(i * 4 + wave) * 512]);
      gload_lds16(Bt + (brow0 + row) * K + (size_t)kt * 32 + kc * 8,
                  &lds[buf][1][(i * 4 + wave) * 512]);
    }
  };
  auto compute = [&](int buf) {
    bf16x8 af[4], bfr[4];
#pragma unroll
    for (int m = 0; m < 4; ++m) {
      int r = wr * 64 + m * 16 + l15;
      af[m] = *(const bf16x8*)&lds[buf][0][r * 32 + (lhi ^ ((r >> 1) & 3)) * 8];
    }
#pragma unroll
    for (int n = 0; n < 4; ++n) {
      int r = wc * 64 + n * 16 + l15;
      bfr[n] = *(const bf16x8*)&lds[buf][1][r * 32 + (lhi ^ ((r >> 1) & 3)) * 8];
    }
#pragma unroll
    for (int m = 0; m < 4; ++m)
#pragma unroll
      for (int n = 0; n < 4; ++n)
        acc[m][n] = MFMA16(af[m], bfr[n], acc[m][n]);
  };

  stage(0, 0);
  stage(1, 1);
  asm volatile("s_waitcnt vmcnt(4)" ::: "memory");
  __builtin_amdgcn_s_barrier();
  asm volatile("" ::: "memory");

  for (int t = 0; t < nkt; ++t) {
    const int cur = t % 3;
    const bool pf2 = (t + 2 < nkt);
    if (pf2) stage((t + 2) % 3, t + 2);
    compute(cur);
    if (t + 1 < nkt) {
      if (pf2) asm volatile("s_waitcnt vmcnt(4)" ::: "memory");
      else     asm volatile("s_waitcnt vmcnt(0)" ::: "memory");
      __builtin_amdgcn_s_barrier();
      asm volatile("" ::: "memory");
    }
  }

#pragma unroll
  for (int m = 0; m < 4; ++m) {
    int row = bm * 128 + wr * 64 + m * 16 + lhi * 4;
#pragma unroll
    for (int n = 0; n < 4; ++n) {
      int col = bn * 128 + wc * 64 + n * 16 + l15;
      if (EP == 0 && col >= 2048) {
        int h = (col - 2048) >> 6, ch = (col - 2048) & 63;
        int b = row >> 10, s0 = row & 1023;
        u16* vt = (u16*)residp;
        union { u16 o[4]; uint64_t u; } pk;
#pragma unroll
        for (int r = 0; r < 4; ++r) pk.o[r] = f2bf(acc[m][n][r]);
        *(uint64_t*)&vt[((size_t)(b * 16 + h) * 64 + ch) * 1024 + s0] = pk.u;
        continue;
      }
#pragma unroll
      for (int r = 0; r < 4; ++r) {
        int rr = row + r;
        float v = acc[m][n][r];
        if (EP == 0) {
          ((u16*)outp)[(size_t)rr * N + col] = f2bf(v);
        } else if (EP == 1) {
          ((u16*)outp)[(size_t)rr * N + col] = f2bf(gelu_f(v + bias[col]));
        } else if (EP == 2) {
          float t2 = v + bias[col];
          int b = rr >> 10;
          float res = ((const float*)residp)[(size_t)rr * N + col];
          ((u16*)outp)[(size_t)rr * N + col] =
              f2bf(res + gate[(size_t)b * 6144 + col] * t2);
        } else {
          float t2 = v + bias[col];
          int b = rr >> 10;
          float res = bf2f(((const u16*)residp)[(size_t)rr * N + col]);
          ((float*)outp)[(size_t)rr * N + col] = res + gate[(size_t)b * 6144 + col] * t2;
        }
      }
    }
  }
}

// ==== GEMM8 (attempt #3, mlp1 only): m201-style 256x256 8-phase, BK=64, 512 thr ====
// 2 LDS buffers (128KB, 1 blk/CU). Fixes vs failed R6/R7 ports:
//  (1) XCD bijective swizzle (R6's 155MB refetch made it HBM-latency-bound),
//  (2) rule-18 fencing: asm lgkmcnt(0) + sched_barrier(0) after each phase barrier,
//  (3) memory-clobbered barriers so the scheduler can't smear phases.
// Per K-tile kt (cur=kt&1), 4 phases {issue reads/stage; bar; lgkm0+SB; prio1 16 MFMA
// prio0; bar}: ph0 reads A-mh0(8)+B-n01(4); ph1 reads B-n23(4); ph2 reads A-mh1(8) +
// stage B-halves(kt+2); ph3 stages A-halves(kt+2), then vmcnt(8) (retires kt+1's 8
// loads; kt+2's 8 stay in flight). Staging ordering: B rows fully read after ph1's
// drain (bfr01 ph0, bfr23 ph1, each lgkm-drained before its closing barrier) ->
// B-stage at ph2 is barrier-separated; A rows fully read after ph2 -> A-stage at ph3.
__global__ __launch_bounds__(512, 1)
void gemm8_k(const u16* __restrict__ A, const u16* __restrict__ Bt,
             int N, int K,
             const float* __restrict__ bias, u16* __restrict__ outp) {
  __shared__ __align__(16) u16 As[2][256 * 64];
  __shared__ __align__(16) u16 Bs[2][256 * 64];
  const int nwg = gridDim.x * gridDim.y;          // 512 for mlp1 (nwg % 8 == 0)
  int bid = blockIdx.y * gridDim.x + blockIdx.x;
  int swz = (bid & 7) * (nwg >> 3) + (bid >> 3);
  const int bn = swz % gridDim.x, bm = swz / gridDim.x;
  const int tid = threadIdx.x;
  const int wave = tid >> 6, lane = tid & 63;
  const int l15 = lane & 15, lhi = lane >> 4;
  const int wm = wave >> 2, wn = wave & 3;        // 2(M) x 4(N)
  const int nkt = K >> 6;
  const size_t arow0 = (size_t)bm * 256;
  const size_t brow0 = (size_t)bn * 256;

  f32x4 acc[2][4][4] = {};                        // [mh][m][n]

  // stage one 128-row half (16KB): 2 x 16B per lane
  auto stage_half = [&](const u16* mat, size_t row0, u16* dst, int kt) {
    const u16* src = mat + row0 * K + (size_t)kt * 64;
#pragma unroll
    for (int i = 0; i < 2; ++i) {
      int q = i * 512 + tid;
      int r = q >> 3, cc = (q & 7) ^ (r & 7);     // inverse swizzle on SOURCE
      gload_lds16(src + (size_t)r * K + cc * 8, dst + (i * 8 + wave) * 512);
    }
  };
  auto lda = [&](int cur, int row, int kh) -> bf16x8 {
    int cc = (kh * 4 + lhi) ^ (row & 7);
    return *(const bf16x8*)&As[cur][row * 64 + cc * 8];
  };
  auto ldbf = [&](int cur, int row, int kh) -> bf16x8 {
    int cc = (kh * 4 + lhi) ^ (row & 7);
    return *(const bf16x8*)&Bs[cur][row * 64 + cc * 8];
  };

#define PH_BAR()  do { asm volatile("" ::: "memory"); __builtin_amdgcn_s_barrier(); \
                       asm volatile("" ::: "memory"); } while (0)
#define PH_LGKM() do { asm volatile("s_waitcnt lgkmcnt(0)" ::: "memory"); \
                       __builtin_amdgcn_sched_barrier(0); } while (0)

  // prologue: fully stage K-tiles 0 and 1 (8 loads/lane each... 4+4); wait kt0
  stage_half(A,  arow0,       &As[0][0],        0);
  stage_half(A,  arow0 + 128, &As[0][128 * 64], 0);
  stage_half(Bt, brow0,       &Bs[0][0],        0);
  stage_half(Bt, brow0 + 128, &Bs[0][128 * 64], 0);
  stage_half(A,  arow0,       &As[1][0],        1);
  stage_half(A,  arow0 + 128, &As[1][128 * 64], 1);
  stage_half(Bt, brow0,       &Bs[1][0],        1);
  stage_half(Bt, brow0 + 128, &Bs[1][128 * 64], 1);
  asm volatile("s_waitcnt vmcnt(8)" ::: "memory");
  PH_BAR();

  bf16x8 afr[4][2], bfr01[2][2], bfr23[2][2];
  for (int kt = 0; kt < nkt; ++kt) {
    const int cur = kt & 1;
    const bool pf2 = (kt + 2 < nkt);

    // ---- ph0: read A-mh0 + B-n01 ; MFMA mh0 x n01 ----
#pragma unroll
    for (int m = 0; m < 4; ++m) {
      int r = wm * 128 + m * 16 + l15;
      afr[m][0] = lda(cur, r, 0); afr[m][1] = lda(cur, r, 1);
    }
#pragma unroll
    for (int n = 0; n < 2; ++n) {
      int r = wn * 64 + n * 16 + l15;
      bfr01[n][0] = ldbf(cur, r, 0); bfr01[n][1] = ldbf(cur, r, 1);
    }
    PH_BAR(); PH_LGKM();
    __builtin_amdgcn_s_setprio(1);
#pragma unroll
    for (int m = 0; m < 4; ++m)
#pragma unroll
      for (int n = 0; n < 2; ++n) {
        acc[0][m][n] = MFMA16(afr[m][0], bfr01[n][0], acc[0][m][n]);
        acc[0][m][n] = MFMA16(afr[m][1], bfr01[n][1], acc[0][m][n]);
      }
    __builtin_amdgcn_s_setprio(0);
    PH_BAR();

    // ---- ph1: read B-n23 ; MFMA mh0 x n23 ----
#pragma unroll
    for (int n = 0; n < 2; ++n) {
      int r = wn * 64 + (n + 2) * 16 + l15;
      bfr23[n][0] = ldbf(cur, r, 0); bfr23[n][1] = ldbf(cur, r, 1);
    }
    PH_BAR(); PH_LGKM();
    __builtin_amdgcn_s_setprio(1);
#pragma unroll
    for (int m = 0; m < 4; ++m)
#pragma unroll
      for (int n = 0; n < 2; ++n) {
        acc[0][m][n + 2] = MFMA16(afr[m][0], bfr23[n][0], acc[0][m][n + 2]);
        acc[0][m][n + 2] = MFMA16(afr[m][1], bfr23[n][1], acc[0][m][n + 2]);
      }
    __builtin_amdgcn_s_setprio(0);
    PH_BAR();

    // ---- ph2: read A-mh1 ; stage B halves (kt+2) ; MFMA mh1 x n01 ----
#pragma unroll
    for (int m = 0; m < 4; ++m) {
      int r = wm * 128 + 64 + m * 16 + l15;
      afr[m][0] = lda(cur, r, 0); afr[m][1] = lda(cur, r, 1);
    }
    if (pf2) {
      stage_half(Bt, brow0,       &Bs[cur][0],        kt + 2);
      stage_half(Bt, brow0 + 128, &Bs[cur][128 * 64], kt + 2);
    }
    PH_BAR(); PH_LGKM();
    __builtin_amdgcn_s_setprio(1);
#pragma unroll
    for (int m = 0; m < 4; ++m)
#pragma unroll
      for (int n = 0; n < 2; ++n) {
        acc[1][m][n] = MFMA16(afr[m][0], bfr01[n][0], acc[1][m][n]);
        acc[1][m][n] = MFMA16(afr[m][1], bfr01[n][1], acc[1][m][n]);
      }
    __builtin_amdgcn_s_setprio(0);
    PH_BAR();

    // ---- ph3: stage A halves (kt+2) ; MFMA mh1 x n23 ; K-tile checkpoint ----
    if (pf2) {
      stage_half(A, arow0,       &As[cur][0],        kt + 2);
      stage_half(A, arow0 + 128, &As[cur][128 * 64], kt + 2);
    }
    PH_BAR();
    __builtin_amdgcn_s_setprio(1);
#pragma unroll
    for (int m = 0; m < 4; ++m)
#pragma unroll
      for (int n = 0; n < 2; ++n) {
        acc[1][m][n + 2] = MFMA16(afr[m][0], bfr23[n][0], acc[1][m][n + 2]);
        acc[1][m][n + 2] = MFMA16(afr[m][1], bfr23[n][1], acc[1][m][n + 2]);
      }
    __builtin_amdgcn_s_setprio(0);
    if (kt + 1 < nkt) {
      if (pf2) asm volatile("s_waitcnt vmcnt(8)" ::: "memory");
      else     asm volatile("s_waitcnt vmcnt(0)" ::: "memory");
      PH_BAR();
    }
  }
#undef PH_BAR
#undef PH_LGKM

  // epilogue: bias + gelu -> bf16
#pragma unroll
  for (int mh = 0; mh < 2; ++mh)
#pragma unroll
    for (int m = 0; m < 4; ++m) {
      int row = bm * 256 + wm * 128 + mh * 64 + m * 16 + lhi * 4;
#pragma unroll
      for (int n = 0; n < 4; ++n) {
        int col = bn * 256 + wn * 64 + n * 16 + l15;
#pragma unroll
        for (int r = 0; r < 4; ++r) {
          int rr = row + r;
          outp[(size_t)rr * N + col] = f2bf(gelu_f(acc[mh][m][n][r] + bias[col]));
        }
      }
    }
}

// ---------------- flash attention (best): QBLK=64, T1 swizzle, fixed-base softmax ----------------
__global__ __launch_bounds__(256)
void attn_k(const u16* __restrict__ qkv, const u16* __restrict__ vt,
            u16* __restrict__ y) {
  int bid0 = blockIdx.x + 16 * (blockIdx.y + 16 * blockIdx.z);
  int swz = (bid0 & 7) * 256 + (bid0 >> 3);
  const int qt = swz & 15, h = (swz >> 4) & 15, b = swz >> 8;
  const int tid = threadIdx.x, wave = tid >> 6, lane = tid & 63;
  const int l15 = lane & 15, lhi = lane >> 4;
  __shared__ __align__(16) u16 Qs[64 * 64];
  __shared__ __align__(16) u16 Ks[2][64 * 64];
  __shared__ __align__(16) u16 Vs[2][64 * 64];
  __shared__ __align__(16) u16 Ps[64 * 64];
  const size_t qrow0 = (size_t)b * 1024 + qt * 64;
  const size_t krow0 = (size_t)b * 1024;
  const size_t vrow0 = (size_t)(b * 16 + h) * 64;

  auto stageQ = [&]() {
#pragma unroll
    for (int i = 0; i < 2; ++i) {
      int c = (i * 4 + wave) * 64 + lane;
      int r = c >> 3, j = (c & 7) ^ (r & 7);
      gload_lds16(qkv + (qrow0 + r) * 3072 + 1024 + h * 64 + j * 8,
                  &Qs[(i * 4 + wave) * 512]);
    }
  };
  auto stageKV = [&](int buf, int kt) {
#pragma unroll
    for (int i = 0; i < 2; ++i) {
      int c = (i * 4 + wave) * 64 + lane;
      int r = c >> 3, j = (c & 7) ^ (r & 7);
      gload_lds16(qkv + (krow0 + kt * 64 + r) * 3072 + h * 64 + j * 8,
                  &Ks[buf][(i * 4 + wave) * 512]);
      gload_lds16(vt + (vrow0 + r) * 1024 + kt * 64 + j * 8,
                  &Vs[buf][(i * 4 + wave) * 512]);
    }
  };
  auto ldb = [](const u16* base, int row, int cc) -> bf16x8 {
    return *(const bf16x8*)&base[row * 64 + ((cc ^ (row & 7)) << 3)];
  };

  stageQ();
  stageKV(0, 0);
  __syncthreads();
  bf16x8 qf[2];
  qf[0] = ldb(Qs, wave * 16 + l15, lhi);
  qf[1] = ldb(Qs, wave * 16 + l15, 4 + lhi);

  bf16x8 ones;
#pragma unroll
  for (int j = 0; j < 8; ++j) ones[j] = (__bf16)1.0f;

  f32x4 o[5] = {};   // o[4] = softmax denominator (ones-column MFMA)

  for (int kt = 0; kt < 16; ++kt) {
    int cur = kt & 1;
    if (kt < 15) stageKV(cur ^ 1, kt + 1);
    f32x4 sf[4] = {};
    __builtin_amdgcn_s_setprio(1);
#pragma unroll
    for (int n = 0; n < 4; ++n) {
      bf16x8 k0 = ldb(Ks[cur], n * 16 + l15, lhi);
      bf16x8 k1 = ldb(Ks[cur], n * 16 + l15, 4 + lhi);
      sf[n] = MFMA16(qf[0], k0, sf[n]);
      sf[n] = MFMA16(qf[1], k1, sf[n]);
    }
    __builtin_amdgcn_s_setprio(0);
#pragma unroll
    for (int r = 0; r < 4; ++r) {
      int row = wave * 16 + lhi * 4 + r;
      int rb = row * 64, sw = (row & 7) << 3;
      Ps[rb + (l15 ^ sw)]        = f2bf(__expf(sf[0][r]));
      Ps[rb + ((l15 + 16) ^ sw)] = f2bf(__expf(sf[1][r]));
      Ps[rb + ((l15 + 32) ^ sw)] = f2bf(__expf(sf[2][r]));
      Ps[rb + ((l15 + 48) ^ sw)] = f2bf(__expf(sf[3][r]));
    }
    bf16x8 pf0 = ldb(Ps, wave * 16 + l15, lhi);
    bf16x8 pf1 = ldb(Ps, wave * 16 + l15, 4 + lhi);
    __builtin_amdgcn_s_setprio(1);
#pragma unroll
    for (int n = 0; n < 4; ++n) {
      bf16x8 v0 = ldb(Vs[cur], n * 16 + l15, lhi);
      bf16x8 v1 = ldb(Vs[cur], n * 16 + l15, 4 + lhi);
      o[n] = MFMA16(pf0, v0, o[n]);
      o[n] = MFMA16(pf1, v1, o[n]);
    }
    o[4] = MFMA16(pf0, ones, o[4]);
    o[4] = MFMA16(pf1, ones, o[4]);
    __builtin_amdgcn_s_setprio(0);
    __syncthreads();
  }
#pragma unroll
  for (int r = 0; r < 4; ++r) {
    float inv = 1.0f / o[4][r];
    size_t yrow = (qrow0 + wave * 16 + lhi * 4 + r) * 1024 + h * 64 + l15;
    y[yrow]      = f2bf(o[0][r] * inv);
    y[yrow + 16] = f2bf(o[1][r] * inv);
    y[yrow + 32] = f2bf(o[2][r] * inv);
    y[yrow + 48] = f2bf(o[3][r] * inv);
  }
}

// ---------------- host ----------------
extern "C" void kernel_launch(void* const* d_in, const int* in_sizes, int n_in,
                              void* d_out, int out_size, void* d_ws, size_t ws_size,
                              hipStream_t stream) {
  const float* x      = (const float*)d_in[0];
  const float* c      = (const float*)d_in[1];
  const float* w_ada  = (const float*)d_in[2];
  const float* b_ada  = (const float*)d_in[3];
  const float* w_qkv  = (const float*)d_in[4];
  const float* w_proj = (const float*)d_in[5];
  const float* b_proj = (const float*)d_in[6];
  const float* w_mlp1 = (const float*)d_in[7];
  const float* b_mlp1 = (const float*)d_in[8];
  const float* w_mlp2 = (const float*)d_in[9];
  const float* b_mlp2 = (const float*)d_in[10];
  float* out = (float*)d_out;

  char* ws = (char*)d_ws;
  size_t off = 0;
  auto alloc = [&](size_t bytes) {
    void* p = ws + off;
    off += (bytes + 255) & ~(size_t)255;
    return p;
  };
  float* cmod  = (float*)alloc((size_t)8 * 6144 * 4);
  float* apart = (float*)alloc((size_t)32 * 8 * 6144 * 4);
  u16* wqkvT   = (u16*)alloc((size_t)3072 * 1024 * 2);
  u16* wprojT  = (u16*)alloc((size_t)1024 * 1024 * 2);
  u16* wmlp1T  = (u16*)alloc((size_t)4096 * 1024 * 2);
  u16* wmlp2T  = (u16*)alloc((size_t)1024 * 4096 * 2);
  u16* xmod    = (u16*)alloc((size_t)8192 * 1024 * 2);   // reused as attention out y
  u16* qkv     = (u16*)alloc((size_t)8192 * 3072 * 2);   // front reused as x_mod2
  u16* vt      = (u16*)alloc((size_t)8 * 16 * 64 * 1024 * 2);
  u16* x1      = (u16*)alloc((size_t)8192 * 1024 * 2);   // residual stream, bf16
  u16* hbuf    = (u16*)alloc((size_t)8192 * 4096 * 2);
  u16* ybuf  = xmod;   // x_mod dead after qkv GEMM
  u16* xmod2 = qkv;    // qkv dead after attention

  prep_k<<<3840, 256, 0, stream>>>(w_qkv, w_proj, w_mlp1, w_mlp2,
                                   wqkvT, wprojT, wmlp1T, wmlp2T,
                                   c, w_ada, apart);
  adaln_red_k<<<192, 256, 0, stream>>>(apart, b_ada, cmod);
  lnmod_k<<<8192, 256, 0, stream>>>(x, cmod, 0, 1024, xmod);
  gemm_k<0><<<dim3(3072 / 128, 8192 / 128), 256, 0, stream>>>(
      xmod, wqkvT, 3072, 1024, nullptr, vt, nullptr, qkv);   // V fused-transposed into vt
  attn_k<<<dim3(16, 16, 8), 256, 0, stream>>>(qkv, vt, ybuf);
  gemm_k<2><<<dim3(1024 / 128, 8192 / 128), 256, 0, stream>>>(
      ybuf, wprojT, 1024, 1024, b_proj, x, cmod + 2048, x1);
  lnmodb_k<<<8192, 256, 0, stream>>>(x1, cmod, 3072, 4096, xmod2);
  gemm8_k<<<dim3(4096 / 256, 8192 / 256), 512, 0, stream>>>(
      xmod2, wmlp1T, 4096, 1024, b_mlp1, hbuf);              // 8-phase attempt #3
  gemm_k<3><<<dim3(1024 / 128, 8192 / 128), 256, 0, stream>>>(
      hbuf, wmlp2T, 1024, 4096, b_mlp2, x1, cmod + 5120, out);
}